// Round 2
// baseline (1613.641 us; speedup 1.0000x reference)
//
#include <hip/hip_runtime.h>
#include <hip/hip_bf16.h>
#include <cstdint>

#define DEV __device__ __forceinline__

typedef float    f32x4 __attribute__((ext_vector_type(4)));
typedef __bf16   bf8_t __attribute__((ext_vector_type(8)));
typedef unsigned short us8 __attribute__((ext_vector_type(8)));

DEV unsigned short bf(float f) {
  union { __hip_bfloat16 h; unsigned short u; } x;
  x.h = __float2bfloat16(f);
  return x.u;
}
DEV float fb(unsigned short u) {
  union { unsigned int u; float f; } x;
  x.u = (unsigned int)u << 16;
  return x.f;
}
DEV f32x4 mfma(bf8_t a, bf8_t b, f32x4 c) {
  return __builtin_amdgcn_mfma_f32_16x16x32_bf16(a, b, c, 0, 0, 0);
}

// weight arena offsets (bf16 elements) inside d_ws
#define OFF_QKV   0
#define OFF_OUT   49152
#define OFF_CONVP 65536
#define OFF_PW1   81920
#define OFF_TOK   98304
#define OFF_LPW   114688
#define OFF_FC1   131072
#define OFF_FC2   196608
#define W_TOTAL   262144

// ---------------- K0: convert weights to bf16 ----------------
__global__ __launch_bounds__(256)
void k_prep(const float* __restrict__ qkv_w, const float* __restrict__ out_w,
            const float* __restrict__ convp_w, const float* __restrict__ pw1_w,
            const float* __restrict__ tok_w, const float* __restrict__ lpw_w,
            const float* __restrict__ fc1_w, const float* __restrict__ fc2_w,
            unsigned short* __restrict__ Wb) {
  int i = blockIdx.x * 256 + threadIdx.x;
  float v;
  if      (i < OFF_OUT)   v = qkv_w[i - OFF_QKV];
  else if (i < OFF_CONVP) v = out_w[i - OFF_OUT];
  else if (i < OFF_PW1)   v = convp_w[i - OFF_CONVP];
  else if (i < OFF_TOK)   v = pw1_w[i - OFF_PW1];
  else if (i < OFF_LPW)   v = tok_w[i - OFF_TOK];
  else if (i < OFF_FC1)   v = lpw_w[i - OFF_LPW];
  else if (i < OFF_FC2)   v = fc1_w[i - OFF_FC1];
  else                    v = fc2_w[i - OFF_FC2];
  Wb[i] = bf(v);
}

// ---------------- K1: fused remsa block (one 8x8 window per block) ----------------
// LN1 -> qkv -> head-mix attn -> outproj(acc) -> convp -> pw1 -> dw(tok axis)
// -> tok(acc chained) -> y = x + acc (fp32, NCHW to d_out) -> LN2 -> lpw -> L1(bf16 NHWC)
__global__ __launch_bounds__(256, 2)
void k_remsa(const float* __restrict__ x, const float* __restrict__ n1w,
             const float* __restrict__ n1b, const unsigned short* __restrict__ Wb,
             const float* __restrict__ qkv_b, const float* __restrict__ pos_bias,
             const float* __restrict__ out_b, const float* __restrict__ convp_b,
             const float* __restrict__ pw1_b, const float* __restrict__ dw1_w,
             const float* __restrict__ dw1_b, const float* __restrict__ tok_b,
             const float* __restrict__ n2w, const float* __restrict__ n2b,
             float* __restrict__ yout, unsigned short* __restrict__ L1) {
  extern __shared__ char smem[];
  unsigned short* XN = (unsigned short*)smem;            // [64][136] bf16: xn -> t2 -> z
  unsigned short* AO = (unsigned short*)(smem + 17408);  // [64][136] bf16: ao -> t1 -> t3
  float*          XS = (float*)(smem + 34816);           // [64][132] f32 x-tile / [128][66] yt
  unsigned short* QK = (unsigned short*)(smem + 34816);  // [16][392] bf16 qkv tile
  float*          RED = (float*)(smem + 68608);          // 512 partials + 64 mu + 64 rs

  const int t = threadIdx.x;
  const int l = t & 63, w = t >> 6;
  const int lr = l & 15, lhi = l >> 4;
  const int R0 = w * 16;

  const int win = blockIdx.x;
  const int b = win >> 10, rem = win & 1023, hb = rem >> 5, wb = rem & 31;
  const float* xb = x + (size_t)b * 128 * 65536 + (size_t)(hb * 8) * 256 + wb * 8;

  const unsigned short* Wq  = Wb + OFF_QKV;
  const unsigned short* Wo  = Wb + OFF_OUT;
  const unsigned short* Wc  = Wb + OFF_CONVP;
  const unsigned short* Wp  = Wb + OFF_PW1;
  const unsigned short* Wt  = Wb + OFF_TOK;
  const unsigned short* Wl  = Wb + OFF_LPW;

  // per-lane epilogue constants (col = j*16 + lr)
  float ob[8], tb[8], w2[8], b2[8];
#pragma unroll
  for (int j = 0; j < 8; j++) {
    int c = j * 16 + lr;
    ob[j] = out_b[c]; tb[j] = tok_b[c]; w2[j] = n2w[c]; b2[j] = n2b[c];
  }

  // ---- stage x tile (fp32) ----
  for (int i = t; i < 2048; i += 256) {
    int c = i >> 4, rq = i & 15, r = rq >> 1, s4 = (rq & 1) * 4;
    float4 v = *(const float4*)&xb[(size_t)c * 65536 + r * 256 + s4];
    int tok = r * 8 + s4;
    XS[(tok + 0) * 132 + c] = v.x; XS[(tok + 1) * 132 + c] = v.y;
    XS[(tok + 2) * 132 + c] = v.z; XS[(tok + 3) * 132 + c] = v.w;
  }
  __syncthreads();

  // ---- LN1 stats ----
  {
    int tok = t & 63, part = t >> 6;
    float s = 0.f, q = 0.f;
    for (int c = part * 32; c < part * 32 + 32; c++) {
      float v = XS[tok * 132 + c]; s += v; q += v * v;
    }
    RED[part * 64 + tok] = s; RED[256 + part * 64 + tok] = q;
  }
  __syncthreads();
  if (t < 64) {
    float s = RED[t] + RED[64 + t] + RED[128 + t] + RED[192 + t];
    float q = RED[256 + t] + RED[320 + t] + RED[384 + t] + RED[448 + t];
    float mu = s * 0.0078125f;
    float var = q * 0.0078125f - mu * mu;
    RED[512 + t] = mu;
    RED[576 + t] = rsqrtf(var + 1e-5f);
  }
  __syncthreads();

  // ---- xn (bf16) ----
  {
    int tok = t & 63, qtr = t >> 6;
    float mu = RED[512 + tok], rs = RED[576 + tok];
#pragma unroll
    for (int j8 = 0; j8 < 4; j8++) {
      int c0 = qtr * 32 + j8 * 8;
      us8 p;
#pragma unroll
      for (int jj = 0; jj < 8; jj++) {
        int c = c0 + jj;
        p[jj] = bf((XS[tok * 132 + c] - mu) * rs * n1w[c] + n1b[c]);
      }
      *(us8*)&XN[tok * 136 + c0] = p;
    }
  }
  __syncthreads();

  // ---- qkv GEMM + per-token head-mixing attention (4 tiles of 16 tokens) ----
  for (int tt = 0; tt < 4; tt++) {
    bf8_t a[4];
#pragma unroll
    for (int kk = 0; kk < 4; kk++)
      a[kk] = *(const bf8_t*)&XN[(tt * 16 + lr) * 136 + kk * 32 + lhi * 8];
#pragma unroll
    for (int j = 0; j < 6; j++) {
      int o0 = w * 96 + j * 16;
      f32x4 acc = {0.f, 0.f, 0.f, 0.f};
#pragma unroll
      for (int kk = 0; kk < 4; kk++) {
        bf8_t bfr = *(const bf8_t*)&Wq[(size_t)(o0 + lr) * 128 + kk * 32 + lhi * 8];
        acc = mfma(a[kk], bfr, acc);
      }
      float bias = qkv_b[o0 + lr];
#pragma unroll
      for (int reg = 0; reg < 4; reg++)
        QK[(lhi * 4 + reg) * 392 + o0 + lr] = bf(acc[reg] + bias);
    }
    __syncthreads();
    if (t < 128) {
      int lt = t >> 3, hh = t & 7, n = tt * 16 + lt;
      const unsigned short* row = &QK[lt * 392];
      float qv[16];
#pragma unroll
      for (int d = 0; d < 16; d++) qv[d] = fb(row[hh * 48 + d]);
      float sc[8], mx = -1e30f;
#pragma unroll
      for (int g = 0; g < 8; g++) {
        float s = 0.f;
#pragma unroll
        for (int d = 0; d < 16; d++) s += qv[d] * fb(row[g * 48 + 16 + d]);
        s = s * 0.25f + pos_bias[n * 64 + hh * 8 + g];
        sc[g] = s; mx = fmaxf(mx, s);
      }
      float den = 0.f;
#pragma unroll
      for (int g = 0; g < 8; g++) { sc[g] = __expf(sc[g] - mx); den += sc[g]; }
      float inv = 1.f / den;
      us8 p0, p1;
#pragma unroll
      for (int d = 0; d < 16; d++) {
        float o = 0.f;
#pragma unroll
        for (int g = 0; g < 8; g++) o += sc[g] * fb(row[g * 48 + 32 + d]);
        if (d < 8) p0[d] = bf(o * inv); else p1[d - 8] = bf(o * inv);
      }
      *(us8*)&AO[n * 136 + hh * 16] = p0;
      *(us8*)&AO[n * 136 + hh * 16 + 8] = p1;
    }
    __syncthreads();
  }

  // ---- out-proj GEMM -> acc1 (kept in regs, chained with tok GEMM later) ----
  f32x4 acc1[8];
#pragma unroll
  for (int j = 0; j < 8; j++) acc1[j] = (f32x4){0.f, 0.f, 0.f, 0.f};
  {
    bf8_t a[4];
#pragma unroll
    for (int kk = 0; kk < 4; kk++)
      a[kk] = *(const bf8_t*)&AO[(R0 + lr) * 136 + kk * 32 + lhi * 8];
#pragma unroll
    for (int j = 0; j < 8; j++) {
      int o0 = j * 16;
#pragma unroll
      for (int kk = 0; kk < 4; kk++) {
        bf8_t bfr = *(const bf8_t*)&Wo[(size_t)(o0 + lr) * 128 + kk * 32 + lhi * 8];
        acc1[j] = mfma(a[kk], bfr, acc1[j]);
      }
    }
  }

  // ---- convp GEMM (reads XN) ----
  f32x4 acc2[8];
#pragma unroll
  for (int j = 0; j < 8; j++) acc2[j] = (f32x4){0.f, 0.f, 0.f, 0.f};
  {
    bf8_t a[4];
#pragma unroll
    for (int kk = 0; kk < 4; kk++)
      a[kk] = *(const bf8_t*)&XN[(R0 + lr) * 136 + kk * 32 + lhi * 8];
#pragma unroll
    for (int j = 0; j < 8; j++) {
#pragma unroll
      for (int kk = 0; kk < 4; kk++) {
        bf8_t bfr = *(const bf8_t*)&Wc[(size_t)(j * 16 + lr) * 128 + kk * 32 + lhi * 8];
        acc2[j] = mfma(a[kk], bfr, acc2[j]);
      }
    }
  }
  __syncthreads();   // all AO/XN reads done
  // write t1 -> AO buffer
#pragma unroll
  for (int j = 0; j < 8; j++) {
    float bias = convp_b[j * 16 + lr];
#pragma unroll
    for (int reg = 0; reg < 4; reg++)
      AO[(R0 + lhi * 4 + reg) * 136 + j * 16 + lr] = bf(acc2[j][reg] + bias);
  }
  __syncthreads();

  // ---- pw1 GEMM (t1 -> t2 into XN buffer) ----
#pragma unroll
  for (int j = 0; j < 8; j++) acc2[j] = (f32x4){0.f, 0.f, 0.f, 0.f};
  {
    bf8_t a[4];
#pragma unroll
    for (int kk = 0; kk < 4; kk++)
      a[kk] = *(const bf8_t*)&AO[(R0 + lr) * 136 + kk * 32 + lhi * 8];
#pragma unroll
    for (int j = 0; j < 8; j++) {
#pragma unroll
      for (int kk = 0; kk < 4; kk++) {
        bf8_t bfr = *(const bf8_t*)&Wp[(size_t)(j * 16 + lr) * 128 + kk * 32 + lhi * 8];
        acc2[j] = mfma(a[kk], bfr, acc2[j]);
      }
    }
  }
  __syncthreads();
#pragma unroll
  for (int j = 0; j < 8; j++) {
    float bias = pw1_b[j * 16 + lr];
#pragma unroll
    for (int reg = 0; reg < 4; reg++)
      XN[(R0 + lhi * 4 + reg) * 136 + j * 16 + lr] = bf(acc2[j][reg] + bias);
  }
  __syncthreads();

  // ---- depthwise conv along token axis (t2 -> t3 into AO buffer) ----
  for (int i = t; i < 8192; i += 256) {
    int n = i >> 7, c = i & 127;
    float v = dw1_b[c] + dw1_w[c * 3 + 1] * fb(XN[n * 136 + c]);
    if (n > 0)  v += dw1_w[c * 3 + 0] * fb(XN[(n - 1) * 136 + c]);
    if (n < 63) v += dw1_w[c * 3 + 2] * fb(XN[(n + 1) * 136 + c]);
    AO[n * 136 + c] = bf(v);
  }
  __syncthreads();

  // ---- tok GEMM chained into acc1 ----
  {
    bf8_t a[4];
#pragma unroll
    for (int kk = 0; kk < 4; kk++)
      a[kk] = *(const bf8_t*)&AO[(R0 + lr) * 136 + kk * 32 + lhi * 8];
#pragma unroll
    for (int j = 0; j < 8; j++) {
#pragma unroll
      for (int kk = 0; kk < 4; kk++) {
        bf8_t bfr = *(const bf8_t*)&Wt[(size_t)(j * 16 + lr) * 128 + kk * 32 + lhi * 8];
        acc1[j] = mfma(a[kk], bfr, acc1[j]);
      }
    }
  }
  __syncthreads();   // BUF2 free again

  // ---- re-stage x tile ----
  for (int i = t; i < 2048; i += 256) {
    int c = i >> 4, rq = i & 15, r = rq >> 1, s4 = (rq & 1) * 4;
    float4 v = *(const float4*)&xb[(size_t)c * 65536 + r * 256 + s4];
    int tok = r * 8 + s4;
    XS[(tok + 0) * 132 + c] = v.x; XS[(tok + 1) * 132 + c] = v.y;
    XS[(tok + 2) * 132 + c] = v.z; XS[(tok + 3) * 132 + c] = v.w;
  }
  __syncthreads();

  // ---- y = x + acc1 + biases; LN2 stats in-register ----
  float sreg[4] = {0.f, 0.f, 0.f, 0.f}, qreg[4] = {0.f, 0.f, 0.f, 0.f};
#pragma unroll
  for (int j = 0; j < 8; j++) {
#pragma unroll
    for (int reg = 0; reg < 4; reg++) {
      int row = R0 + lhi * 4 + reg, col = j * 16 + lr;
      float y = acc1[j][reg] + ob[j] + tb[j] + XS[row * 132 + col];
      acc1[j][reg] = y;
      sreg[reg] += y; qreg[reg] += y * y;
    }
  }
#pragma unroll
  for (int m = 1; m < 16; m <<= 1) {
#pragma unroll
    for (int reg = 0; reg < 4; reg++) {
      sreg[reg] += __shfl_xor(sreg[reg], m, 64);
      qreg[reg] += __shfl_xor(qreg[reg], m, 64);
    }
  }
  float mu[4], rs[4];
#pragma unroll
  for (int reg = 0; reg < 4; reg++) {
    mu[reg] = sreg[reg] * 0.0078125f;
    float var = qreg[reg] * 0.0078125f - mu[reg] * mu[reg];
    rs[reg] = rsqrtf(var + 1e-5f);
  }
  __syncthreads();   // all XS(x) reads done; BUF2 -> yt
  float* YT = XS;    // [128][66]
#pragma unroll
  for (int j = 0; j < 8; j++) {
#pragma unroll
    for (int reg = 0; reg < 4; reg++) {
      int row = R0 + lhi * 4 + reg, col = j * 16 + lr;
      float y = acc1[j][reg];
      YT[col * 66 + row] = y;
      XN[row * 136 + col] = bf((y - mu[reg]) * rs[reg] * w2[j] + b2[j]);  // z
    }
  }
  __syncthreads();

  // ---- transpose-store y -> d_out (NCHW) ----
  for (int i = t; i < 2048; i += 256) {
    int c = i >> 4, p4 = (i & 15) * 4;
    int r = p4 >> 3, s = p4 & 7;
    float4 v = {YT[c * 66 + p4], YT[c * 66 + p4 + 1], YT[c * 66 + p4 + 2], YT[c * 66 + p4 + 3]};
    *(float4*)&yout[((size_t)(b * 128 + c)) * 65536 + (size_t)(hb * 8 + r) * 256 + wb * 8 + s] = v;
  }

  // ---- lpw GEMM (z -> l1, no bias), store bf16 NHWC ----
  {
    bf8_t a[4];
#pragma unroll
    for (int kk = 0; kk < 4; kk++)
      a[kk] = *(const bf8_t*)&XN[(R0 + lr) * 136 + kk * 32 + lhi * 8];
#pragma unroll
    for (int j = 0; j < 8; j++) {
      f32x4 acc = {0.f, 0.f, 0.f, 0.f};
#pragma unroll
      for (int kk = 0; kk < 4; kk++) {
        bf8_t bfr = *(const bf8_t*)&Wl[(size_t)(j * 16 + lr) * 128 + kk * 32 + lhi * 8];
        acc = mfma(a[kk], bfr, acc);
      }
#pragma unroll
      for (int reg = 0; reg < 4; reg++) {
        int row = R0 + lhi * 4 + reg;
        size_t pix = ((size_t)b * 256 + hb * 8 + (row >> 3)) * 256 + wb * 8 + (row & 7);
        L1[pix * 128 + j * 16 + lr] = bf(acc[reg]);
      }
    }
  }
}

// ---------------- K2: 3x3 depthwise conv (bf16 NHWC) ----------------
__global__ __launch_bounds__(256)
void k_dw3(const unsigned short* __restrict__ L1, const float* __restrict__ dwW,
           const float* __restrict__ dwB, unsigned short* __restrict__ L2) {
  size_t tid = (size_t)blockIdx.x * 256 + threadIdx.x;
  int c4 = (int)(tid & 31) * 4;
  size_t pixi = tid >> 5;
  int b = (int)(pixi >> 16), rr = (int)(pixi & 65535), h = rr >> 8, w = rr & 255;
  float acc[4] = {dwB[c4], dwB[c4 + 1], dwB[c4 + 2], dwB[c4 + 3]};
#pragma unroll
  for (int i = 0; i < 3; i++) {
    int h2 = h + i - 1;
    if (h2 < 0 || h2 > 255) continue;
#pragma unroll
    for (int j = 0; j < 3; j++) {
      int w2 = w + j - 1;
      if (w2 < 0 || w2 > 255) continue;
      const unsigned short* p = &L1[(((size_t)b * 256 + h2) * 256 + w2) * 128 + c4];
      uint2 raw = *(const uint2*)p;
      unsigned short e0 = raw.x & 0xffff, e1 = raw.x >> 16, e2 = raw.y & 0xffff, e3 = raw.y >> 16;
      acc[0] += fb(e0) * dwW[(c4 + 0) * 9 + i * 3 + j];
      acc[1] += fb(e1) * dwW[(c4 + 1) * 9 + i * 3 + j];
      acc[2] += fb(e2) * dwW[(c4 + 2) * 9 + i * 3 + j];
      acc[3] += fb(e3) * dwW[(c4 + 3) * 9 + i * 3 + j];
    }
  }
  uint2 o;
  o.x = (unsigned int)bf(acc[0]) | ((unsigned int)bf(acc[1]) << 16);
  o.y = (unsigned int)bf(acc[2]) | ((unsigned int)bf(acc[3]) << 16);
  *(uint2*)&L2[pixi * 128 + c4] = o;
}

// ---------------- K3: fc1 + GELU(erf) + fc2 + residual + NCHW out ----------------
__global__ __launch_bounds__(256, 2)
void k_ffn(const unsigned short* __restrict__ L2, const unsigned short* __restrict__ Wb,
           const float* __restrict__ fc1_b, const float* __restrict__ fc2_b,
           float* __restrict__ out) {
  extern __shared__ char smem[];
  unsigned short* ZT = (unsigned short*)smem;            // [64][136]
  unsigned short* HS = (unsigned short*)(smem + 17408);  // [64][136]
  float*          YT = (float*)(smem + 34816);           // [128][66]

  const int t = threadIdx.x;
  const int l = t & 63, w = t >> 6;
  const int lr = l & 15, lhi = l >> 4;
  const int R0 = w * 16;

  size_t pix0 = (size_t)blockIdx.x * 64;
  const int b = (int)(pix0 >> 16), h = (int)((pix0 >> 8) & 255), w0 = (int)(pix0 & 255);

  const unsigned short* W1 = Wb + OFF_FC1;
  const unsigned short* W2 = Wb + OFF_FC2;

  for (int i = t; i < 1024; i += 256) {
    int n = i >> 4, c8 = (i & 15) * 8;
    *(us8*)&ZT[n * 136 + c8] = *(const us8*)&L2[(pix0 + n) * 128 + c8];
  }
  __syncthreads();

  bf8_t a1[4];
#pragma unroll
  for (int kk = 0; kk < 4; kk++)
    a1[kk] = *(const bf8_t*)&ZT[(R0 + lr) * 136 + kk * 32 + lhi * 8];

  f32x4 facc[8];
#pragma unroll
  for (int j = 0; j < 8; j++) facc[j] = (f32x4){0.f, 0.f, 0.f, 0.f};

  for (int chunk = 0; chunk < 4; chunk++) {
    int hc = chunk * 128;
#pragma unroll
    for (int j = 0; j < 8; j++) {
      f32x4 hacc = {0.f, 0.f, 0.f, 0.f};
#pragma unroll
      for (int kk = 0; kk < 4; kk++) {
        bf8_t bfr = *(const bf8_t*)&W1[(size_t)(hc + j * 16 + lr) * 128 + kk * 32 + lhi * 8];
        hacc = mfma(a1[kk], bfr, hacc);
      }
      float bias = fc1_b[hc + j * 16 + lr];
#pragma unroll
      for (int reg = 0; reg < 4; reg++) {
        float v = hacc[reg] + bias;
        float g = 0.5f * v * (1.0f + erff(v * 0.70710678118f));
        HS[(R0 + lhi * 4 + reg) * 136 + j * 16 + lr] = bf(g);
      }
    }
    __syncthreads();
    bf8_t a2[4];
#pragma unroll
    for (int kk = 0; kk < 4; kk++)
      a2[kk] = *(const bf8_t*)&HS[(R0 + lr) * 136 + kk * 32 + lhi * 8];
#pragma unroll
    for (int j = 0; j < 8; j++) {
#pragma unroll
      for (int kk = 0; kk < 4; kk++) {
        bf8_t bfr = *(const bf8_t*)&W2[(size_t)(j * 16 + lr) * 512 + hc + kk * 32 + lhi * 8];
        facc[j] = mfma(a2[kk], bfr, facc[j]);
      }
    }
    __syncthreads();
  }

  // write fc2 result (+bias) into YT[c][p]
#pragma unroll
  for (int j = 0; j < 8; j++) {
    float bias = fc2_b[j * 16 + lr];
#pragma unroll
    for (int reg = 0; reg < 4; reg++)
      YT[(j * 16 + lr) * 66 + R0 + lhi * 4 + reg] = facc[j][reg] + bias;
  }
  __syncthreads();
  // residual: YT += y (read from d_out, NCHW, coalesced)
  for (int i = t; i < 2048; i += 256) {
    int c = i >> 4, p4 = (i & 15) * 4;
    float4 v = *(const float4*)&out[((size_t)(b * 128 + c)) * 65536 + (size_t)h * 256 + w0 + p4];
    YT[c * 66 + p4 + 0] += v.x; YT[c * 66 + p4 + 1] += v.y;
    YT[c * 66 + p4 + 2] += v.z; YT[c * 66 + p4 + 3] += v.w;
  }
  __syncthreads();
  for (int i = t; i < 2048; i += 256) {
    int c = i >> 4, p4 = (i & 15) * 4;
    float4 v = {YT[c * 66 + p4], YT[c * 66 + p4 + 1], YT[c * 66 + p4 + 2], YT[c * 66 + p4 + 3]};
    *(float4*)&out[((size_t)(b * 128 + c)) * 65536 + (size_t)h * 256 + w0 + p4] = v;
  }
}

// ---------------- launch ----------------
extern "C" void kernel_launch(void* const* d_in, const int* in_sizes, int n_in,
                              void* d_out, int out_size, void* d_ws, size_t ws_size,
                              hipStream_t stream) {
  const float* x       = (const float*)d_in[0];
  const float* norm1_w = (const float*)d_in[1];
  const float* norm1_b = (const float*)d_in[2];
  const float* qkv_w   = (const float*)d_in[3];
  const float* qkv_b   = (const float*)d_in[4];
  const float* pos_b   = (const float*)d_in[5];
  const float* out_w   = (const float*)d_in[6];
  const float* out_b   = (const float*)d_in[7];
  const float* convp_w = (const float*)d_in[8];
  const float* convp_b = (const float*)d_in[9];
  const float* pw1_w   = (const float*)d_in[10];
  const float* pw1_b   = (const float*)d_in[11];
  const float* dw1_w   = (const float*)d_in[12];
  const float* dw1_b   = (const float*)d_in[13];
  const float* tok_w   = (const float*)d_in[14];
  const float* tok_b   = (const float*)d_in[15];
  const float* norm2_w = (const float*)d_in[16];
  const float* norm2_b = (const float*)d_in[17];
  const float* lpw_w   = (const float*)d_in[18];
  const float* ldw_w   = (const float*)d_in[19];
  const float* ldw_b   = (const float*)d_in[20];
  const float* fc1_w   = (const float*)d_in[21];
  const float* fc1_b   = (const float*)d_in[22];
  const float* fc2_w   = (const float*)d_in[23];
  const float* fc2_b   = (const float*)d_in[24];
  float* out = (float*)d_out;

  // workspace: Wb (512KB bf16 weights) @0, L1 bf16 @1MB, L2 bf16 @1MB+64MB  => ~129MB
  unsigned short* Wbf = (unsigned short*)d_ws;
  unsigned short* L1  = (unsigned short*)((char*)d_ws + (1u << 20));
  unsigned short* L2  = (unsigned short*)((char*)d_ws + (1u << 20) + (64u << 20));

  // allow >64KB dynamic LDS (gfx950 has 160KB)
  hipFuncSetAttribute((const void*)k_remsa, hipFuncAttributeMaxDynamicSharedMemorySize, 71168);
  hipFuncSetAttribute((const void*)k_ffn,   hipFuncAttributeMaxDynamicSharedMemorySize, 68608);

  k_prep<<<1024, 256, 0, stream>>>(qkv_w, out_w, convp_w, pw1_w, tok_w, lpw_w,
                                   fc1_w, fc2_w, Wbf);
  k_remsa<<<4096, 256, 71168, stream>>>(x, norm1_w, norm1_b, Wbf, qkv_b, pos_b,
                                        out_b, convp_b, pw1_b, dw1_w, dw1_b, tok_b,
                                        norm2_w, norm2_b, out, L1);
  k_dw3<<<32768, 256, 0, stream>>>(L1, ldw_w, ldw_b, L2);
  k_ffn<<<4096, 256, 68608, stream>>>(L2, Wbf, fc1_b, fc2_b, out);
}